// Round 16
// baseline (142.956 us; speedup 1.0000x reference)
//
#include <hip/hip_runtime.h>
#include <math.h>

#define SC 4
#define BB 2
#define CC 32
#define HH 256
#define WW 512
#define CH (HH / SC)   // 64
#define CW (WW / SC)   // 128

using f16x8 = __attribute__((ext_vector_type(8))) _Float16;
using f16x4 = __attribute__((ext_vector_type(4))) _Float16;
using f32x4 = __attribute__((ext_vector_type(4))) float;
using f32x2 = __attribute__((ext_vector_type(2))) float;

// Direction metadata (output channel order: c, l, r, t, b, lt, rt, lb, rb)
//   s0: 0 -> xv (x[w%4]), 1 -> 4-(w%4) (D1), 2 -> (w%4)+1 (D2)
//   s1: 0 -> yv (x[h%4]), 1 -> 4-(h%4) (D3), 2 -> (h%4)+1 (D4)
constexpr int K_dh[9] = {0, 0, 0, -1, 1, -1, -1, 1, 1};
constexpr int K_dw[9] = {0, -1, 1, 0, 0, -1, 1, -1, 1};
constexpr int K_s0[9] = {0, 1, 2, 0, 0, 1, 2, 0, 0};
constexpr int K_s1[9] = {0, 0, 0, 1, 2, 0, 0, 1, 2};

__device__ __forceinline__ float swz_x16(float v) {
    // lane ^ 16 within each 32-lane half: BitMode offset = (16<<10)|0x1F
    return __int_as_float(__builtin_amdgcn_ds_swizzle(__float_as_int(v), 0x401F));
}

// LESSONS carried:
//  - R3: never force 8 waves/EU via __launch_bounds__ (allocator splits the
//    file and spills ~80MB to scratch).
//  - R7: no quad-tile (compiler rematerializes; ILP saturates at 2 chains).
//  - R10/R11/R12 bisect: multi-output inline asm whose outputs can alias
//    (two "+v" holding equal values) gets register-coalesced into a
//    self-swap -> silent wrong answers. No aliasable asm.
//  - R14: textual phase-batching is ignored by the scheduler; source-level
//    instruction order cannot force chain overlap.
//  - R15: MFMA-layer-4 neutral -> per-(d,tile) chain is latency-BALANCED;
//    no single op class dominates. Intra-kernel levers exhausted.
//  - R16 (this round): single-variable test of the FUSED staging path —
//    drop the alr_prepass launch entirely; each block computes its own
//    30-cell ALr halo inline (lr is 2MB, L2/L3-resident; 3.75x redundancy).

// MFMA main, R16 = R13 (best PASSING, dur 139.3) with the PREPASS FUSED.
// Launch sequence was 2 serial kernels (64-block under-occupied prepass +
// main); the main kernel's inline-staging path computes identical f32 sums
// (same fmaf order -> absmax unchanged) for +1-3us inline cost, saving the
// prepass duration + one graph-node launch boundary.
// Carried structure (R12/R13): dual-tile (2048 blocks, 256 thr, 4 waves,
// 32 px/wave), f32 s_alr, swapped layer-2 (D2[ch2][px]), in-lane K16
// layer-3 (v_mfma_f32_16x16x16f16, w2A rows>=8 zero), DS layer-4 reduce,
// fused single-softmax tail with lane<32 contiguous stores.
__global__ __launch_bounds__(256, 4) void ercm_mfma(const float* __restrict__ hr,
                                                    const float* __restrict__ lr,
                                                    const float* __restrict__ w0,
                                                    const float* __restrict__ w1,
                                                    const float* __restrict__ w2,
                                                    const float* __restrict__ w3,
                                                    float* __restrict__ out) {
    __shared__ float    s_alr[30 * 40];     // [cell][o] FP32, 3 x 10 halo, stride 40 (160B rows)
    __shared__ _Float16 s_ahr[4][32 * 40];  // per wave: [px 0..31][o] (both tiles)

    const int tid = threadIdx.x;
    const int lane = tid & 63;
    const int ty = tid >> 6;       // wave id = h-row within block
    const int m16 = lane & 15;
    const int q = lane >> 4;       // quad
    const int bx = blockIdx.x;     // 0..15
    const int by = blockIdx.y;     // 0..63
    const int b = blockIdx.z;      // 0..1
    const int h = by * 4 + ty;
    const int wp0 = bx * 32;
    const size_t HW = (size_t)HH * WW;

    // ---- stage ALr halo tile (3 x 10 coarse cells), FP32, computed INLINE ----
    // Per item (cell,o): 32 lr loads (uniform across the 32 threads sharing a
    // cell -> broadcast, L1/L2 hit; lr is 2MB = L2/L3-resident) + 32 fmaf in
    // the same order as the old prepass -> bit-identical staged values.
    {
        const int cy0 = by, cx0 = bx * 8;
        for (int i = tid; i < 30 * 32; i += 256) {
            const int o = i & 31, cell = i >> 5;
            const int row = cell / 10, col = cell - row * 10;
            const int gcy = cy0 - 1 + row, gcx = cx0 - 1 + col;
            float a = 0.f;
            if ((unsigned)gcy < (unsigned)CH && (unsigned)gcx < (unsigned)CW) {
                const float* lp = lr + (size_t)b * CC * CH * CW + (size_t)gcy * CW + gcx;
#pragma unroll
                for (int c = 0; c < 32; c++) a = fmaf(lp[(size_t)c * (CH * CW)], w0[o * 66 + c], a);
            }
            s_alr[cell * 40 + o] = a;
        }
    }

    // ---- load weight fragments (once). Same lane layout serves A or B. ----
    f16x8 w1B, w0hB0, w0hB1;
    f16x4 w2A;  // 16x16x16 A-frag: [m=ch3=m16][k=ch2=q*4+j], rows>=8 zero
    {
        const float* p1 = w1 + m16 * 32 + q * 8;
        const float* p00 = w0 + m16 * 66 + 32 + q * 8;
        const float* p01 = w0 + (m16 + 16) * 66 + 32 + q * 8;
#pragma unroll
        for (int j = 0; j < 8; j++) {
            w1B[j] = (_Float16)p1[j];
            w0hB0[j] = (_Float16)p00[j];
            w0hB1[j] = (_Float16)p01[j];
        }
        const bool w2ok = (m16 < 8);
#pragma unroll
        for (int j = 0; j < 4; j++)
            w2A[j] = (_Float16)(w2ok ? w2[m16 * 16 + q * 4 + j] : 0.f);
    }
    // layer-1 distance weights for this lane's channels o=q*8+j, as f32x2 pairs
    f32x2 w0d0v[4], w0d1v[4];
#pragma unroll
    for (int jp = 0; jp < 4; jp++) {
        w0d0v[jp] = f32x2{w0[(q * 8 + 2 * jp) * 66 + 64], w0[(q * 8 + 2 * jp + 1) * 66 + 64]};
        w0d1v[jp] = f32x2{w0[(q * 8 + 2 * jp) * 66 + 65], w0[(q * 8 + 2 * jp + 1) * 66 + 65]};
    }
    // layer-4 weights per D3 row ch3 = q*4+r (rows >=8 are exact zeros)
    float w3c[4];
#pragma unroll
    for (int r = 0; r < 4; r++) w3c[r] = (q < 2) ? w3[q * 4 + r] : 0.f;

    // per-lane distance operand values (pixel phase xm = w%4; ym wave-uniform)
    const int xm = m16 & 3;
    const float xv = (float)(xm < 2 ? xm - 2 : xm - 1);
    const float x1 = (float)(4 - xm), x2 = (float)(xm + 1);
    const int ym = h & 3;
    const float yv = (float)(ym < 2 ? ym - 2 : ym - 1);
    const float y1 = (float)(4 - ym), y2 = (float)(ym + 1);

    _Float16* sa = s_ahr[ty];

    __syncthreads();  // s_alr staged (everything else is per-wave)

    const float* hp = hr + (size_t)b * CC * HW + (size_t)h * WW + wp0;

    // ---- Phase A, both tiles: ahr = hr . w0hr via 4 MFMAs (D[px][ch]) ----
    f16x8 aT0, aT1;
#pragma unroll
    for (int j = 0; j < 8; j++) {
        aT0[j] = (_Float16)hp[(size_t)(q * 8 + j) * HW + m16];
        aT1[j] = (_Float16)hp[(size_t)(q * 8 + j) * HW + 16 + m16];
    }
    {
        f32x4 p00 = {0.f, 0.f, 0.f, 0.f}, p01 = {0.f, 0.f, 0.f, 0.f};
        f32x4 p10 = {0.f, 0.f, 0.f, 0.f}, p11 = {0.f, 0.f, 0.f, 0.f};
        p00 = __builtin_amdgcn_mfma_f32_16x16x32_f16(aT0, w0hB0, p00, 0, 0, 0);
        p01 = __builtin_amdgcn_mfma_f32_16x16x32_f16(aT0, w0hB1, p01, 0, 0, 0);
        p10 = __builtin_amdgcn_mfma_f32_16x16x32_f16(aT1, w0hB0, p10, 0, 0, 0);
        p11 = __builtin_amdgcn_mfma_f32_16x16x32_f16(aT1, w0hB1, p11, 0, 0, 0);
#pragma unroll
        for (int r = 0; r < 4; r++) {
            const int row = q * 4 + r;
            sa[row * 40 + m16] = (_Float16)p00[r];
            sa[row * 40 + 16 + m16] = (_Float16)p01[r];
            sa[(16 + row) * 40 + m16] = (_Float16)p10[r];
            sa[(16 + row) * 40 + 16 + m16] = (_Float16)p11[r];
        }
    }
    // hoist ahr to f32 registers ONCE per tile (reused by all 9 directions)
    const f16x8 ahv0 = *(const f16x8*)&sa[m16 * 40 + q * 8];
    const f16x8 ahv1 = *(const f16x8*)&sa[(16 + m16) * 40 + q * 8];
    f32x2 ah0[4], ah1[4];
#pragma unroll
    for (int jp = 0; jp < 4; jp++) {
        ah0[jp] = f32x2{(float)ahv0[2 * jp], (float)ahv0[2 * jp + 1]};
        ah1[jp] = f32x2{(float)ahv1[2 * jp], (float)ahv1[2 * jp + 1]};
    }

    // alr halo bases per tile (FP32); per-d cell adds a compile-time offset
    // ((1+dh)*10 + (1+dw)) * 40 floats.
    const float* alp0 = &s_alr[(m16 >> 2) * 40 + q * 8];
    const float* alp1 = &s_alr[(4 + (m16 >> 2)) * 40 + q * 8];
    const int wown0 = wp0 + m16;        // this lane's pixel, tile 0 (q-uniform)
    const int wown1 = wp0 + 16 + m16;   // tile 1

    float l0[9], l1[9];
#pragma unroll
    for (int d = 0; d < 9; d++) {
        const int dh = K_dh[d], dw = K_dw[d];
        const float d0 = (K_s0[d] == 0) ? xv : ((K_s0[d] == 1) ? x1 : x2);
        const float d1 = (K_s1[d] == 0) ? yv : ((K_s1[d] == 1) ? y1 : y2);
        const f32x2 d0v = {d0, d0}, d1v = {d1, d1};
        const int off = ((1 + dh) * 10 + (1 + dw)) * 40;

        // shared per-d distance contribution (t-invariant)
        f32x2 dd[4];
#pragma unroll
        for (int jp = 0; jp < 4; jp++)
            dd[jp] = __builtin_elementwise_fma(w0d0v[jp], d0v, w0d1v[jp] * d1v);

        // layer 1 (both tiles): A1[k=ch1][n=px] = leaky(ahr + alr + dd)
        // alr FP32 in LDS: two b128 reads per tile, no cvt chain.
        const f32x2* al0 = (const f32x2*)(alp0 + off);
        const f32x2* al1 = (const f32x2*)(alp1 + off);
        f16x8 a1_0, a1_1;
#pragma unroll
        for (int jp = 0; jp < 4; jp++) {
            f32x2 v0 = ah0[jp] + al0[jp];
            f32x2 v1 = ah1[jp] + al1[jp];
            v0 = v0 + dd[jp];
            v1 = v1 + dd[jp];
            v0 = __builtin_elementwise_max(v0, v0 * 0.01f);
            v1 = __builtin_elementwise_max(v1, v1 * 0.01f);
            a1_0[2 * jp] = (_Float16)v0[0];
            a1_0[2 * jp + 1] = (_Float16)v0[1];
            a1_1[2 * jp] = (_Float16)v1[0];
            a1_1[2 * jp + 1] = (_Float16)v1[1];
        }
        // layer 2 SWAPPED: D2[ch2][px] (lane: rows ch2=q*4+r, col px=m16)
        f32x4 c2_0 = {0.f, 0.f, 0.f, 0.f}, c2_1 = {0.f, 0.f, 0.f, 0.f};
        c2_0 = __builtin_amdgcn_mfma_f32_16x16x32_f16(w1B, a1_0, c2_0, 0, 0, 0);
        c2_1 = __builtin_amdgcn_mfma_f32_16x16x32_f16(w1B, a1_1, c2_1, 0, 0, 0);

        // layer2->3 glue: pure in-lane. D2 rows ch2=q*4+r ARE the 16x16x16
        // B-frag k-rows (k=q*4+r) -> b3 = pack(leaky(c2)).
        f16x4 b3_0, b3_1;
#pragma unroll
        for (int r = 0; r < 4; r++) {
            const float e0 = fmaxf(c2_0[r], 0.01f * c2_0[r]);
            const float e1 = fmaxf(c2_1[r], 0.01f * c2_1[r]);
            b3_0[r] = (_Float16)e0;
            b3_1[r] = (_Float16)e1;
        }
        // layer 3 (16x16x16, K=ch2=16 exact): D3[ch3=q*4+r][px=m16];
        // rows ch3>=8 exact 0 (w2A rows zero)
        f32x4 c3_0 = {0.f, 0.f, 0.f, 0.f}, c3_1 = {0.f, 0.f, 0.f, 0.f};
        c3_0 = __builtin_amdgcn_mfma_f32_16x16x16f16(w2A, b3_0, c3_0, 0, 0, 0);
        c3_1 = __builtin_amdgcn_mfma_f32_16x16x16f16(w2A, b3_1, c3_1, 0, 0, 0);

        // layer 4: in-lane fma over ch3=q*4+r, then sum the 4 q-partials
        // (lanes m16+16q) with swz(x16) + shfl(x32) — proven reduce; result
        // replicated in ALL 64 lanes by construction.
        {
            float part = 0.f;
#pragma unroll
            for (int r = 0; r < 4; r++) {
                const float lv = fmaxf(c3_0[r], 0.01f * c3_0[r]);
                part = fmaf(w3c[r], lv, part);
            }
            float s2 = part + swz_x16(part);
            const float lg = s2 + __shfl_xor(s2, 32, 64);
            const bool ok = ((unsigned)(h + 4 * dh) < (unsigned)HH) &&
                            ((unsigned)(wown0 + 4 * dw) < (unsigned)WW);
            l0[d] = ok ? lg : -100.0f;
        }
        {
            float part = 0.f;
#pragma unroll
            for (int r = 0; r < 4; r++) {
                const float lv = fmaxf(c3_1[r], 0.01f * c3_1[r]);
                part = fmaf(w3c[r], lv, part);
            }
            float s2 = part + swz_x16(part);
            const float lg = s2 + __shfl_xor(s2, 32, 64);
            const bool ok = ((unsigned)(h + 4 * dh) < (unsigned)HH) &&
                            ((unsigned)(wown1 + 4 * dw) < (unsigned)WW);
            l1[d] = ok ? lg : -100.0f;
        }
    }

    // fused tail: logits replicated in all 64 lanes (DS reduce), so each
    // lane selects its own pixel's 9 logits and runs ONE softmax chain.
    // lanes 0..15 -> tile0 px wp0+lane; lanes 16..31 -> tile1 px wp0+lane.
    float ld[9];
#pragma unroll
    for (int d = 0; d < 9; d++) ld[d] = (lane & 16) ? l1[d] : l0[d];
    float mx = ld[0];
#pragma unroll
    for (int d = 1; d < 9; d++) mx = fmaxf(mx, ld[d]);
    float s = 0.f;
#pragma unroll
    for (int d = 0; d < 9; d++) {
        ld[d] = __expf(ld[d] - mx);
        s += ld[d];
    }
    const float inv = __builtin_amdgcn_rcpf(s);
    if (lane < 32) {  // 32 writer lanes -> 9 contiguous 128B stores (both tiles)
        float* op = out + (size_t)b * 9 * HW + (size_t)h * WW + (wp0 + lane);
#pragma unroll
        for (int d = 0; d < 9; d++) op[(size_t)d * HW] = ld[d] * inv;
    }
}

extern "C" void kernel_launch(void* const* d_in, const int* in_sizes, int n_in,
                              void* d_out, int out_size, void* d_ws, size_t ws_size,
                              hipStream_t stream) {
    const float* lr = (const float*)d_in[0];
    const float* hr = (const float*)d_in[1];
    // d_in[2], d_in[3] (lr_feature_r / hr_feature_r) are unused by the reference.
    const float* w0 = (const float*)d_in[4];
    const float* w1 = (const float*)d_in[5];
    const float* w2 = (const float*)d_in[6];
    const float* w3 = (const float*)d_in[7];
    float* out = (float*)d_out;

    // Single fused kernel: the ALr halo is computed inline per block (lr is
    // 2MB, L2/L3-resident; 3.75x redundancy). Removes the 64-block
    // under-occupied prepass and one graph-node launch boundary.
    dim3 grid(WW / 32, HH / 4, BB);  // 2048 blocks of 256 thr (4 waves)
    ercm_mfma<<<grid, 256, 0, stream>>>(hr, lr, w0, w1, w2, w3, out);
}

// Round 17
// 140.479 us; speedup vs baseline: 1.0176x; 1.0176x over previous
//
#include <hip/hip_runtime.h>
#include <math.h>

#define SC 4
#define BB 2
#define CC 32
#define HH 256
#define WW 512
#define CH (HH / SC)   // 64
#define CW (WW / SC)   // 128

using f16x8 = __attribute__((ext_vector_type(8))) _Float16;
using f16x4 = __attribute__((ext_vector_type(4))) _Float16;
using f32x4 = __attribute__((ext_vector_type(4))) float;
using f32x2 = __attribute__((ext_vector_type(2))) float;

// Direction metadata (output channel order: c, l, r, t, b, lt, rt, lb, rb)
//   s0: 0 -> xv (x[w%4]), 1 -> 4-(w%4) (D1), 2 -> (w%4)+1 (D2)
//   s1: 0 -> yv (x[h%4]), 1 -> 4-(h%4) (D3), 2 -> (h%4)+1 (D4)
constexpr int K_dh[9] = {0, 0, 0, -1, 1, -1, -1, 1, 1};
constexpr int K_dw[9] = {0, -1, 1, 0, 0, -1, 1, -1, 1};
constexpr int K_s0[9] = {0, 1, 2, 0, 0, 1, 2, 0, 0};
constexpr int K_s1[9] = {0, 0, 0, 1, 2, 0, 0, 1, 2};

__device__ __forceinline__ float swz_x16(float v) {
    // lane ^ 16 within each 32-lane half: BitMode offset = (16<<10)|0x1F
    return __int_as_float(__builtin_amdgcn_ds_swizzle(__float_as_int(v), 0x401F));
}

// LESSONS carried:
//  - R3: never force 8 waves/EU via __launch_bounds__ (allocator splits the
//    file and spills ~80MB to scratch).
//  - R7: no quad-tile (compiler rematerializes; ILP saturates at 2 chains).
//  - R10/R11/R12 bisect: multi-output inline asm whose outputs can alias
//    (two "+v" holding equal values) gets register-coalesced into a
//    self-swap -> silent wrong answers. No aliasable asm.
//  - R14: textual phase-batching is ignored by the scheduler; source-level
//    instruction order cannot force chain overlap.
//  - R15: MFMA layer-4 neutral -> the per-(d,tile) chain is latency-BALANCED.
//  - R16: fusing the prepass REGRESSED (+3.5us inline cost > prepass+launch
//    savings; FETCH 17.8->22.2MB). Keep the 2-kernel workspace path.
//  - R17 (this round): Phase A is independent of s_alr -> moved BEFORE the
//    barrier so staging-drain + barrier wait hide under Phase A's HBM
//    latency and MFMA compute (pure code motion, bit-identical output).

// Pre-pass: ALr[(b*CH+cy)*CW+cx][o] = sum_c w0[o*66+c] * lr[b][c][cy][cx]  (fp32)
__global__ __launch_bounds__(256) void alr_prepass(const float* __restrict__ lr,
                                                   const float* __restrict__ w0,
                                                   float* __restrict__ alr) {
    const int idx = blockIdx.x * 256 + threadIdx.x;
    if (idx >= BB * CH * CW) return;
    const int b = idx / (CH * CW);
    const int cell = idx - b * (CH * CW);
    const float* lp = lr + (size_t)b * CC * CH * CW + cell;
    float lv[32];
#pragma unroll
    for (int c = 0; c < 32; c++) lv[c] = lp[(size_t)c * (CH * CW)];
    float acc[32];
#pragma unroll
    for (int o = 0; o < 32; o++) {
        float a = 0.f;
#pragma unroll
        for (int c = 0; c < 32; c++) a = fmaf(lv[c], w0[o * 66 + c], a);
        acc[o] = a;
    }
    float4* op = (float4*)(alr + (size_t)idx * 32);
#pragma unroll
    for (int j = 0; j < 8; j++)
        op[j] = make_float4(acc[4 * j], acc[4 * j + 1], acc[4 * j + 2], acc[4 * j + 3]);
}

// MFMA main, R17 = R13 (best PASSING, dur 139.3) + PHASE-A HOIST.
// The single __syncthreads protects only s_alr; Phase A (hr loads, 4 MFMAs,
// per-wave s_ahr write + ahr hoist) has no s_alr dependency, so it now runs
// BEFORE the barrier: the staging loads' vmcnt drain and the barrier wait
// overlap with Phase A's ~500cy HBM latency + MFMA compute instead of
// serializing in front of it. Pure statement reorder -> bit-identical output.
// Carried structure (R12/R13): dual-tile (2048 blocks, 256 thr, 4 waves,
// 32 px/wave), f32 s_alr, swapped layer-2 (D2[ch2][px]), in-lane K16
// layer-3 (v_mfma_f32_16x16x16f16, w2A rows>=8 zero), DS layer-4 reduce,
// fused single-softmax tail with lane<32 contiguous stores.
template <bool USE_WS>
__global__ __launch_bounds__(256, 4) void ercm_mfma(const float* __restrict__ hr,
                                                    const float* __restrict__ lr,
                                                    const float* __restrict__ alr,
                                                    const float* __restrict__ w0,
                                                    const float* __restrict__ w1,
                                                    const float* __restrict__ w2,
                                                    const float* __restrict__ w3,
                                                    float* __restrict__ out) {
    __shared__ float    s_alr[30 * 40];     // [cell][o] FP32, 3 x 10 halo, stride 40 (160B rows)
    __shared__ _Float16 s_ahr[4][32 * 40];  // per wave: [px 0..31][o] (both tiles)

    const int tid = threadIdx.x;
    const int lane = tid & 63;
    const int ty = tid >> 6;       // wave id = h-row within block
    const int m16 = lane & 15;
    const int q = lane >> 4;       // quad
    const int bx = blockIdx.x;     // 0..15
    const int by = blockIdx.y;     // 0..63
    const int b = blockIdx.z;      // 0..1
    const int h = by * 4 + ty;
    const int wp0 = bx * 32;
    const size_t HW = (size_t)HH * WW;

    // ---- stage ALr halo tile (3 x 10 coarse cells), FP32 ----
    const int cy0 = by, cx0 = bx * 8;
    if (USE_WS) {
        for (int i = tid; i < 30 * 32; i += 256) {
            const int c = i & 31, cell = i >> 5;
            const int row = cell / 10, col = cell - row * 10;
            const int gcy = cy0 - 1 + row, gcx = cx0 - 1 + col;
            float v = 0.f;
            if ((unsigned)gcy < (unsigned)CH && (unsigned)gcx < (unsigned)CW)
                v = alr[(((size_t)b * CH + gcy) * CW + gcx) * 32 + c];
            s_alr[cell * 40 + c] = v;
        }
    } else {
        for (int i = tid; i < 30 * 32; i += 256) {
            const int o = i & 31, cell = i >> 5;
            const int row = cell / 10, col = cell - row * 10;
            const int gcy = cy0 - 1 + row, gcx = cx0 - 1 + col;
            float a = 0.f;
            if ((unsigned)gcy < (unsigned)CH && (unsigned)gcx < (unsigned)CW) {
                const float* lp = lr + (size_t)b * CC * CH * CW + (size_t)gcy * CW + gcx;
#pragma unroll
                for (int c = 0; c < 32; c++) a = fmaf(lp[(size_t)c * (CH * CW)], w0[o * 66 + c], a);
            }
            s_alr[cell * 40 + o] = a;
        }
    }

    // ---- load weight fragments (once). Same lane layout serves A or B. ----
    f16x8 w1B, w0hB0, w0hB1;
    f16x4 w2A;  // 16x16x16 A-frag: [m=ch3=m16][k=ch2=q*4+j], rows>=8 zero
    {
        const float* p1 = w1 + m16 * 32 + q * 8;
        const float* p00 = w0 + m16 * 66 + 32 + q * 8;
        const float* p01 = w0 + (m16 + 16) * 66 + 32 + q * 8;
#pragma unroll
        for (int j = 0; j < 8; j++) {
            w1B[j] = (_Float16)p1[j];
            w0hB0[j] = (_Float16)p00[j];
            w0hB1[j] = (_Float16)p01[j];
        }
        const bool w2ok = (m16 < 8);
#pragma unroll
        for (int j = 0; j < 4; j++)
            w2A[j] = (_Float16)(w2ok ? w2[m16 * 16 + q * 4 + j] : 0.f);
    }
    // layer-1 distance weights for this lane's channels o=q*8+j, as f32x2 pairs
    f32x2 w0d0v[4], w0d1v[4];
#pragma unroll
    for (int jp = 0; jp < 4; jp++) {
        w0d0v[jp] = f32x2{w0[(q * 8 + 2 * jp) * 66 + 64], w0[(q * 8 + 2 * jp + 1) * 66 + 64]};
        w0d1v[jp] = f32x2{w0[(q * 8 + 2 * jp) * 66 + 65], w0[(q * 8 + 2 * jp + 1) * 66 + 65]};
    }
    // layer-4 weights per D3 row ch3 = q*4+r (rows >=8 are exact zeros)
    float w3c[4];
#pragma unroll
    for (int r = 0; r < 4; r++) w3c[r] = (q < 2) ? w3[q * 4 + r] : 0.f;

    // per-lane distance operand values (pixel phase xm = w%4; ym wave-uniform)
    const int xm = m16 & 3;
    const float xv = (float)(xm < 2 ? xm - 2 : xm - 1);
    const float x1 = (float)(4 - xm), x2 = (float)(xm + 1);
    const int ym = h & 3;
    const float yv = (float)(ym < 2 ? ym - 2 : ym - 1);
    const float y1 = (float)(4 - ym), y2 = (float)(ym + 1);

    _Float16* sa = s_ahr[ty];

    const float* hp = hr + (size_t)b * CC * HW + (size_t)h * WW + wp0;

    // ---- Phase A (BEFORE the barrier — no s_alr dependency): both tiles,
    // ahr = hr . w0hr via 4 MFMAs (D[px][ch]) -> per-wave s_ahr ----
    f16x8 aT0, aT1;
#pragma unroll
    for (int j = 0; j < 8; j++) {
        aT0[j] = (_Float16)hp[(size_t)(q * 8 + j) * HW + m16];
        aT1[j] = (_Float16)hp[(size_t)(q * 8 + j) * HW + 16 + m16];
    }
    {
        f32x4 p00 = {0.f, 0.f, 0.f, 0.f}, p01 = {0.f, 0.f, 0.f, 0.f};
        f32x4 p10 = {0.f, 0.f, 0.f, 0.f}, p11 = {0.f, 0.f, 0.f, 0.f};
        p00 = __builtin_amdgcn_mfma_f32_16x16x32_f16(aT0, w0hB0, p00, 0, 0, 0);
        p01 = __builtin_amdgcn_mfma_f32_16x16x32_f16(aT0, w0hB1, p01, 0, 0, 0);
        p10 = __builtin_amdgcn_mfma_f32_16x16x32_f16(aT1, w0hB0, p10, 0, 0, 0);
        p11 = __builtin_amdgcn_mfma_f32_16x16x32_f16(aT1, w0hB1, p11, 0, 0, 0);
#pragma unroll
        for (int r = 0; r < 4; r++) {
            const int row = q * 4 + r;
            sa[row * 40 + m16] = (_Float16)p00[r];
            sa[row * 40 + 16 + m16] = (_Float16)p01[r];
            sa[(16 + row) * 40 + m16] = (_Float16)p10[r];
            sa[(16 + row) * 40 + 16 + m16] = (_Float16)p11[r];
        }
    }
    // hoist ahr to f32 registers ONCE per tile (per-wave buffer, wave-
    // synchronous write->read; compiler inserts lgkmcnt waits — no barrier
    // needed for s_ahr)
    const f16x8 ahv0 = *(const f16x8*)&sa[m16 * 40 + q * 8];
    const f16x8 ahv1 = *(const f16x8*)&sa[(16 + m16) * 40 + q * 8];
    f32x2 ah0[4], ah1[4];
#pragma unroll
    for (int jp = 0; jp < 4; jp++) {
        ah0[jp] = f32x2{(float)ahv0[2 * jp], (float)ahv0[2 * jp + 1]};
        ah1[jp] = f32x2{(float)ahv1[2 * jp], (float)ahv1[2 * jp + 1]};
    }

    __syncthreads();  // s_alr staged (the ONLY cross-wave dependency)

    // alr halo bases per tile (FP32); per-d cell adds a compile-time offset
    // ((1+dh)*10 + (1+dw)) * 40 floats.
    const float* alp0 = &s_alr[(m16 >> 2) * 40 + q * 8];
    const float* alp1 = &s_alr[(4 + (m16 >> 2)) * 40 + q * 8];
    const int wown0 = wp0 + m16;        // this lane's pixel, tile 0 (q-uniform)
    const int wown1 = wp0 + 16 + m16;   // tile 1

    float l0[9], l1[9];
#pragma unroll
    for (int d = 0; d < 9; d++) {
        const int dh = K_dh[d], dw = K_dw[d];
        const float d0 = (K_s0[d] == 0) ? xv : ((K_s0[d] == 1) ? x1 : x2);
        const float d1 = (K_s1[d] == 0) ? yv : ((K_s1[d] == 1) ? y1 : y2);
        const f32x2 d0v = {d0, d0}, d1v = {d1, d1};
        const int off = ((1 + dh) * 10 + (1 + dw)) * 40;

        // shared per-d distance contribution (t-invariant)
        f32x2 dd[4];
#pragma unroll
        for (int jp = 0; jp < 4; jp++)
            dd[jp] = __builtin_elementwise_fma(w0d0v[jp], d0v, w0d1v[jp] * d1v);

        // layer 1 (both tiles): A1[k=ch1][n=px] = leaky(ahr + alr + dd)
        // alr FP32 in LDS: two b128 reads per tile, no cvt chain.
        const f32x2* al0 = (const f32x2*)(alp0 + off);
        const f32x2* al1 = (const f32x2*)(alp1 + off);
        f16x8 a1_0, a1_1;
#pragma unroll
        for (int jp = 0; jp < 4; jp++) {
            f32x2 v0 = ah0[jp] + al0[jp];
            f32x2 v1 = ah1[jp] + al1[jp];
            v0 = v0 + dd[jp];
            v1 = v1 + dd[jp];
            v0 = __builtin_elementwise_max(v0, v0 * 0.01f);
            v1 = __builtin_elementwise_max(v1, v1 * 0.01f);
            a1_0[2 * jp] = (_Float16)v0[0];
            a1_0[2 * jp + 1] = (_Float16)v0[1];
            a1_1[2 * jp] = (_Float16)v1[0];
            a1_1[2 * jp + 1] = (_Float16)v1[1];
        }
        // layer 2 SWAPPED: D2[ch2][px] (lane: rows ch2=q*4+r, col px=m16)
        f32x4 c2_0 = {0.f, 0.f, 0.f, 0.f}, c2_1 = {0.f, 0.f, 0.f, 0.f};
        c2_0 = __builtin_amdgcn_mfma_f32_16x16x32_f16(w1B, a1_0, c2_0, 0, 0, 0);
        c2_1 = __builtin_amdgcn_mfma_f32_16x16x32_f16(w1B, a1_1, c2_1, 0, 0, 0);

        // layer2->3 glue: pure in-lane. D2 rows ch2=q*4+r ARE the 16x16x16
        // B-frag k-rows (k=q*4+r) -> b3 = pack(leaky(c2)).
        f16x4 b3_0, b3_1;
#pragma unroll
        for (int r = 0; r < 4; r++) {
            const float e0 = fmaxf(c2_0[r], 0.01f * c2_0[r]);
            const float e1 = fmaxf(c2_1[r], 0.01f * c2_1[r]);
            b3_0[r] = (_Float16)e0;
            b3_1[r] = (_Float16)e1;
        }
        // layer 3 (16x16x16, K=ch2=16 exact): D3[ch3=q*4+r][px=m16];
        // rows ch3>=8 exact 0 (w2A rows zero)
        f32x4 c3_0 = {0.f, 0.f, 0.f, 0.f}, c3_1 = {0.f, 0.f, 0.f, 0.f};
        c3_0 = __builtin_amdgcn_mfma_f32_16x16x16f16(w2A, b3_0, c3_0, 0, 0, 0);
        c3_1 = __builtin_amdgcn_mfma_f32_16x16x16f16(w2A, b3_1, c3_1, 0, 0, 0);

        // layer 4: in-lane fma over ch3=q*4+r, then sum the 4 q-partials
        // (lanes m16+16q) with swz(x16) + shfl(x32) — proven reduce; result
        // replicated in ALL 64 lanes by construction.
        {
            float part = 0.f;
#pragma unroll
            for (int r = 0; r < 4; r++) {
                const float lv = fmaxf(c3_0[r], 0.01f * c3_0[r]);
                part = fmaf(w3c[r], lv, part);
            }
            float s2 = part + swz_x16(part);
            const float lg = s2 + __shfl_xor(s2, 32, 64);
            const bool ok = ((unsigned)(h + 4 * dh) < (unsigned)HH) &&
                            ((unsigned)(wown0 + 4 * dw) < (unsigned)WW);
            l0[d] = ok ? lg : -100.0f;
        }
        {
            float part = 0.f;
#pragma unroll
            for (int r = 0; r < 4; r++) {
                const float lv = fmaxf(c3_1[r], 0.01f * c3_1[r]);
                part = fmaf(w3c[r], lv, part);
            }
            float s2 = part + swz_x16(part);
            const float lg = s2 + __shfl_xor(s2, 32, 64);
            const bool ok = ((unsigned)(h + 4 * dh) < (unsigned)HH) &&
                            ((unsigned)(wown1 + 4 * dw) < (unsigned)WW);
            l1[d] = ok ? lg : -100.0f;
        }
    }

    // fused tail: logits replicated in all 64 lanes (DS reduce), so each
    // lane selects its own pixel's 9 logits and runs ONE softmax chain.
    // lanes 0..15 -> tile0 px wp0+lane; lanes 16..31 -> tile1 px wp0+lane.
    float ld[9];
#pragma unroll
    for (int d = 0; d < 9; d++) ld[d] = (lane & 16) ? l1[d] : l0[d];
    float mx = ld[0];
#pragma unroll
    for (int d = 1; d < 9; d++) mx = fmaxf(mx, ld[d]);
    float s = 0.f;
#pragma unroll
    for (int d = 0; d < 9; d++) {
        ld[d] = __expf(ld[d] - mx);
        s += ld[d];
    }
    const float inv = __builtin_amdgcn_rcpf(s);
    if (lane < 32) {  // 32 writer lanes -> 9 contiguous 128B stores (both tiles)
        float* op = out + (size_t)b * 9 * HW + (size_t)h * WW + (wp0 + lane);
#pragma unroll
        for (int d = 0; d < 9; d++) op[(size_t)d * HW] = ld[d] * inv;
    }
}

extern "C" void kernel_launch(void* const* d_in, const int* in_sizes, int n_in,
                              void* d_out, int out_size, void* d_ws, size_t ws_size,
                              hipStream_t stream) {
    const float* lr = (const float*)d_in[0];
    const float* hr = (const float*)d_in[1];
    // d_in[2], d_in[3] (lr_feature_r / hr_feature_r) are unused by the reference.
    const float* w0 = (const float*)d_in[4];
    const float* w1 = (const float*)d_in[5];
    const float* w2 = (const float*)d_in[6];
    const float* w3 = (const float*)d_in[7];
    float* out = (float*)d_out;

    const size_t alr_bytes = (size_t)BB * CH * CW * 32 * sizeof(float);  // 2 MB
    dim3 grid(WW / 32, HH / 4, BB);  // 2048 blocks of 256 thr (4 waves)

    if (ws_size >= alr_bytes) {
        float* alr = (float*)d_ws;
        alr_prepass<<<(BB * CH * CW + 255) / 256, 256, 0, stream>>>(lr, w0, alr);
        ercm_mfma<true><<<grid, 256, 0, stream>>>(hr, lr, alr, w0, w1, w2, w3, out);
    } else {
        ercm_mfma<false><<<grid, 256, 0, stream>>>(hr, lr, nullptr, w0, w1, w2, w3, out);
    }
}

// Round 18
// 139.356 us; speedup vs baseline: 1.0258x; 1.0081x over previous
//
#include <hip/hip_runtime.h>
#include <math.h>

#define SC 4
#define BB 2
#define CC 32
#define HH 256
#define WW 512
#define CH (HH / SC)   // 64
#define CW (WW / SC)   // 128

using f16x8 = __attribute__((ext_vector_type(8))) _Float16;
using f16x4 = __attribute__((ext_vector_type(4))) _Float16;
using f32x4 = __attribute__((ext_vector_type(4))) float;
using f32x2 = __attribute__((ext_vector_type(2))) float;

// Direction metadata (output channel order: c, l, r, t, b, lt, rt, lb, rb)
//   s0: 0 -> xv (x[w%4]), 1 -> 4-(w%4) (D1), 2 -> (w%4)+1 (D2)
//   s1: 0 -> yv (x[h%4]), 1 -> 4-(h%4) (D3), 2 -> (h%4)+1 (D4)
constexpr int K_dh[9] = {0, 0, 0, -1, 1, -1, -1, 1, 1};
constexpr int K_dw[9] = {0, -1, 1, 0, 0, -1, 1, -1, 1};
constexpr int K_s0[9] = {0, 1, 2, 0, 0, 1, 2, 0, 0};
constexpr int K_s1[9] = {0, 0, 0, 1, 2, 0, 0, 1, 2};

__device__ __forceinline__ float swz_x16(float v) {
    // lane ^ 16 within each 32-lane half: BitMode offset = (16<<10)|0x1F
    return __int_as_float(__builtin_amdgcn_ds_swizzle(__float_as_int(v), 0x401F));
}

// FINAL KERNEL (R18 = R13, the session's empirical optimum: dur 139.3).
// Plateau evidence: R14 (d-group ILP), R15 (MFMA layer-4), R16 (prepass
// fusion), R17 (Phase-A hoist) all neutral-or-regressing. The kernel is
// latency-bound (VALUBusy 36%, MfmaUtil 4%, HBM 7%), NOT pipe-bound;
// memory traffic is minimal (FETCH=hr+lr ideal, WRITE=output exactly).
// LESSONS carried:
//  - R3: never force 8 waves/EU via __launch_bounds__ (allocator splits the
//    file and spills ~80MB to scratch).
//  - R7: no quad-tile (compiler rematerializes; ILP saturates at 2 chains).
//  - R10/R11/R12 bisect: multi-output inline asm whose outputs can alias
//    (two "+v" holding equal values) gets register-coalesced into a
//    self-swap -> silent wrong answers. No aliasable asm.
//  - R14/R17: the scheduler ignores source-level instruction order.
//  - R16: keep the 2-kernel workspace path (fusion regresses).

// Pre-pass: ALr[(b*CH+cy)*CW+cx][o] = sum_c w0[o*66+c] * lr[b][c][cy][cx]  (fp32)
__global__ __launch_bounds__(256) void alr_prepass(const float* __restrict__ lr,
                                                   const float* __restrict__ w0,
                                                   float* __restrict__ alr) {
    const int idx = blockIdx.x * 256 + threadIdx.x;
    if (idx >= BB * CH * CW) return;
    const int b = idx / (CH * CW);
    const int cell = idx - b * (CH * CW);
    const float* lp = lr + (size_t)b * CC * CH * CW + cell;
    float lv[32];
#pragma unroll
    for (int c = 0; c < 32; c++) lv[c] = lp[(size_t)c * (CH * CW)];
    float acc[32];
#pragma unroll
    for (int o = 0; o < 32; o++) {
        float a = 0.f;
#pragma unroll
        for (int c = 0; c < 32; c++) a = fmaf(lv[c], w0[o * 66 + c], a);
        acc[o] = a;
    }
    float4* op = (float4*)(alr + (size_t)idx * 32);
#pragma unroll
    for (int j = 0; j < 8; j++)
        op[j] = make_float4(acc[4 * j], acc[4 * j + 1], acc[4 * j + 2], acc[4 * j + 3]);
}

// MFMA main. Structure (accumulated over the session, each element A/B-proven):
//  - dual-tile: wave owns 32 px = 2 independent 16-px chains (R6; quad fails R7)
//  - grid 2048 blocks x 256 thr (4 waves), 32 px/wave (R4)
//  - f32 s_alr staging via workspace prepass (R12; f16 cvt chain deleted)
//  - swapped layer-2 MFMA: mfma(w1B, a1) -> D2[ch2][px] (R6)
//  - in-lane K16 layer-3: v_mfma_f32_16x16x16f16(w2A, pack(leaky(c2)));
//    D2 rows ch2=q*4+r ARE the B-frag k-rows -> zero cross-lane glue (R9)
//  - layer-4: in-lane fma + swz_x16 + shfl_xor(32) reduce -> logit
//    replicated in ALL 64 lanes by construction (R9/R12)
//  - fused tail: per-lane select (lane&16 ? l1 : l0), ONE softmax chain,
//    lanes 0..31 -> 9 contiguous 128B stores (R13)
template <bool USE_WS>
__global__ __launch_bounds__(256, 4) void ercm_mfma(const float* __restrict__ hr,
                                                    const float* __restrict__ lr,
                                                    const float* __restrict__ alr,
                                                    const float* __restrict__ w0,
                                                    const float* __restrict__ w1,
                                                    const float* __restrict__ w2,
                                                    const float* __restrict__ w3,
                                                    float* __restrict__ out) {
    __shared__ float    s_alr[30 * 40];     // [cell][o] FP32, 3 x 10 halo, stride 40 (160B rows)
    __shared__ _Float16 s_ahr[4][32 * 40];  // per wave: [px 0..31][o] (both tiles)

    const int tid = threadIdx.x;
    const int lane = tid & 63;
    const int ty = tid >> 6;       // wave id = h-row within block
    const int m16 = lane & 15;
    const int q = lane >> 4;       // quad
    const int bx = blockIdx.x;     // 0..15
    const int by = blockIdx.y;     // 0..63
    const int b = blockIdx.z;      // 0..1
    const int h = by * 4 + ty;
    const int wp0 = bx * 32;
    const size_t HW = (size_t)HH * WW;

    // ---- stage ALr halo tile (3 x 10 coarse cells), FP32 ----
    const int cy0 = by, cx0 = bx * 8;
    if (USE_WS) {
        for (int i = tid; i < 30 * 32; i += 256) {
            const int c = i & 31, cell = i >> 5;
            const int row = cell / 10, col = cell - row * 10;
            const int gcy = cy0 - 1 + row, gcx = cx0 - 1 + col;
            float v = 0.f;
            if ((unsigned)gcy < (unsigned)CH && (unsigned)gcx < (unsigned)CW)
                v = alr[(((size_t)b * CH + gcy) * CW + gcx) * 32 + c];
            s_alr[cell * 40 + c] = v;
        }
    } else {
        for (int i = tid; i < 30 * 32; i += 256) {
            const int o = i & 31, cell = i >> 5;
            const int row = cell / 10, col = cell - row * 10;
            const int gcy = cy0 - 1 + row, gcx = cx0 - 1 + col;
            float a = 0.f;
            if ((unsigned)gcy < (unsigned)CH && (unsigned)gcx < (unsigned)CW) {
                const float* lp = lr + (size_t)b * CC * CH * CW + (size_t)gcy * CW + gcx;
#pragma unroll
                for (int c = 0; c < 32; c++) a = fmaf(lp[(size_t)c * (CH * CW)], w0[o * 66 + c], a);
            }
            s_alr[cell * 40 + o] = a;
        }
    }

    // ---- load weight fragments (once). Same lane layout serves A or B. ----
    f16x8 w1B, w0hB0, w0hB1;
    f16x4 w2A;  // 16x16x16 A-frag: [m=ch3=m16][k=ch2=q*4+j], rows>=8 zero
    {
        const float* p1 = w1 + m16 * 32 + q * 8;
        const float* p00 = w0 + m16 * 66 + 32 + q * 8;
        const float* p01 = w0 + (m16 + 16) * 66 + 32 + q * 8;
#pragma unroll
        for (int j = 0; j < 8; j++) {
            w1B[j] = (_Float16)p1[j];
            w0hB0[j] = (_Float16)p00[j];
            w0hB1[j] = (_Float16)p01[j];
        }
        const bool w2ok = (m16 < 8);
#pragma unroll
        for (int j = 0; j < 4; j++)
            w2A[j] = (_Float16)(w2ok ? w2[m16 * 16 + q * 4 + j] : 0.f);
    }
    // layer-1 distance weights for this lane's channels o=q*8+j, as f32x2 pairs
    f32x2 w0d0v[4], w0d1v[4];
#pragma unroll
    for (int jp = 0; jp < 4; jp++) {
        w0d0v[jp] = f32x2{w0[(q * 8 + 2 * jp) * 66 + 64], w0[(q * 8 + 2 * jp + 1) * 66 + 64]};
        w0d1v[jp] = f32x2{w0[(q * 8 + 2 * jp) * 66 + 65], w0[(q * 8 + 2 * jp + 1) * 66 + 65]};
    }
    // layer-4 weights per D3 row ch3 = q*4+r (rows >=8 are exact zeros)
    float w3c[4];
#pragma unroll
    for (int r = 0; r < 4; r++) w3c[r] = (q < 2) ? w3[q * 4 + r] : 0.f;

    // per-lane distance operand values (pixel phase xm = w%4; ym wave-uniform)
    const int xm = m16 & 3;
    const float xv = (float)(xm < 2 ? xm - 2 : xm - 1);
    const float x1 = (float)(4 - xm), x2 = (float)(xm + 1);
    const int ym = h & 3;
    const float yv = (float)(ym < 2 ? ym - 2 : ym - 1);
    const float y1 = (float)(4 - ym), y2 = (float)(ym + 1);

    _Float16* sa = s_ahr[ty];

    __syncthreads();  // s_alr staged (everything else is per-wave)

    const float* hp = hr + (size_t)b * CC * HW + (size_t)h * WW + wp0;

    // ---- Phase A, both tiles: ahr = hr . w0hr via 4 MFMAs (D[px][ch]) ----
    f16x8 aT0, aT1;
#pragma unroll
    for (int j = 0; j < 8; j++) {
        aT0[j] = (_Float16)hp[(size_t)(q * 8 + j) * HW + m16];
        aT1[j] = (_Float16)hp[(size_t)(q * 8 + j) * HW + 16 + m16];
    }
    {
        f32x4 p00 = {0.f, 0.f, 0.f, 0.f}, p01 = {0.f, 0.f, 0.f, 0.f};
        f32x4 p10 = {0.f, 0.f, 0.f, 0.f}, p11 = {0.f, 0.f, 0.f, 0.f};
        p00 = __builtin_amdgcn_mfma_f32_16x16x32_f16(aT0, w0hB0, p00, 0, 0, 0);
        p01 = __builtin_amdgcn_mfma_f32_16x16x32_f16(aT0, w0hB1, p01, 0, 0, 0);
        p10 = __builtin_amdgcn_mfma_f32_16x16x32_f16(aT1, w0hB0, p10, 0, 0, 0);
        p11 = __builtin_amdgcn_mfma_f32_16x16x32_f16(aT1, w0hB1, p11, 0, 0, 0);
#pragma unroll
        for (int r = 0; r < 4; r++) {
            const int row = q * 4 + r;
            sa[row * 40 + m16] = (_Float16)p00[r];
            sa[row * 40 + 16 + m16] = (_Float16)p01[r];
            sa[(16 + row) * 40 + m16] = (_Float16)p10[r];
            sa[(16 + row) * 40 + 16 + m16] = (_Float16)p11[r];
        }
    }
    // hoist ahr to f32 registers ONCE per tile (reused by all 9 directions)
    const f16x8 ahv0 = *(const f16x8*)&sa[m16 * 40 + q * 8];
    const f16x8 ahv1 = *(const f16x8*)&sa[(16 + m16) * 40 + q * 8];
    f32x2 ah0[4], ah1[4];
#pragma unroll
    for (int jp = 0; jp < 4; jp++) {
        ah0[jp] = f32x2{(float)ahv0[2 * jp], (float)ahv0[2 * jp + 1]};
        ah1[jp] = f32x2{(float)ahv1[2 * jp], (float)ahv1[2 * jp + 1]};
    }

    // alr halo bases per tile (FP32); per-d cell adds a compile-time offset
    // ((1+dh)*10 + (1+dw)) * 40 floats.
    const float* alp0 = &s_alr[(m16 >> 2) * 40 + q * 8];
    const float* alp1 = &s_alr[(4 + (m16 >> 2)) * 40 + q * 8];
    const int wown0 = wp0 + m16;        // this lane's pixel, tile 0 (q-uniform)
    const int wown1 = wp0 + 16 + m16;   // tile 1

    float l0[9], l1[9];
#pragma unroll
    for (int d = 0; d < 9; d++) {
        const int dh = K_dh[d], dw = K_dw[d];
        const float d0 = (K_s0[d] == 0) ? xv : ((K_s0[d] == 1) ? x1 : x2);
        const float d1 = (K_s1[d] == 0) ? yv : ((K_s1[d] == 1) ? y1 : y2);
        const f32x2 d0v = {d0, d0}, d1v = {d1, d1};
        const int off = ((1 + dh) * 10 + (1 + dw)) * 40;

        // shared per-d distance contribution (t-invariant)
        f32x2 dd[4];
#pragma unroll
        for (int jp = 0; jp < 4; jp++)
            dd[jp] = __builtin_elementwise_fma(w0d0v[jp], d0v, w0d1v[jp] * d1v);

        // layer 1 (both tiles): A1[k=ch1][n=px] = leaky(ahr + alr + dd)
        // alr FP32 in LDS: two b128 reads per tile, no cvt chain.
        const f32x2* al0 = (const f32x2*)(alp0 + off);
        const f32x2* al1 = (const f32x2*)(alp1 + off);
        f16x8 a1_0, a1_1;
#pragma unroll
        for (int jp = 0; jp < 4; jp++) {
            f32x2 v0 = ah0[jp] + al0[jp];
            f32x2 v1 = ah1[jp] + al1[jp];
            v0 = v0 + dd[jp];
            v1 = v1 + dd[jp];
            v0 = __builtin_elementwise_max(v0, v0 * 0.01f);
            v1 = __builtin_elementwise_max(v1, v1 * 0.01f);
            a1_0[2 * jp] = (_Float16)v0[0];
            a1_0[2 * jp + 1] = (_Float16)v0[1];
            a1_1[2 * jp] = (_Float16)v1[0];
            a1_1[2 * jp + 1] = (_Float16)v1[1];
        }
        // layer 2 SWAPPED: D2[ch2][px] (lane: rows ch2=q*4+r, col px=m16)
        f32x4 c2_0 = {0.f, 0.f, 0.f, 0.f}, c2_1 = {0.f, 0.f, 0.f, 0.f};
        c2_0 = __builtin_amdgcn_mfma_f32_16x16x32_f16(w1B, a1_0, c2_0, 0, 0, 0);
        c2_1 = __builtin_amdgcn_mfma_f32_16x16x32_f16(w1B, a1_1, c2_1, 0, 0, 0);

        // layer2->3 glue: pure in-lane. D2 rows ch2=q*4+r ARE the 16x16x16
        // B-frag k-rows (k=q*4+r) -> b3 = pack(leaky(c2)).
        f16x4 b3_0, b3_1;
#pragma unroll
        for (int r = 0; r < 4; r++) {
            const float e0 = fmaxf(c2_0[r], 0.01f * c2_0[r]);
            const float e1 = fmaxf(c2_1[r], 0.01f * c2_1[r]);
            b3_0[r] = (_Float16)e0;
            b3_1[r] = (_Float16)e1;
        }
        // layer 3 (16x16x16, K=ch2=16 exact): D3[ch3=q*4+r][px=m16];
        // rows ch3>=8 exact 0 (w2A rows zero)
        f32x4 c3_0 = {0.f, 0.f, 0.f, 0.f}, c3_1 = {0.f, 0.f, 0.f, 0.f};
        c3_0 = __builtin_amdgcn_mfma_f32_16x16x16f16(w2A, b3_0, c3_0, 0, 0, 0);
        c3_1 = __builtin_amdgcn_mfma_f32_16x16x16f16(w2A, b3_1, c3_1, 0, 0, 0);

        // layer 4: in-lane fma over ch3=q*4+r, then sum the 4 q-partials
        // (lanes m16+16q) with swz(x16) + shfl(x32) — proven reduce; result
        // replicated in ALL 64 lanes by construction.
        {
            float part = 0.f;
#pragma unroll
            for (int r = 0; r < 4; r++) {
                const float lv = fmaxf(c3_0[r], 0.01f * c3_0[r]);
                part = fmaf(w3c[r], lv, part);
            }
            float s2 = part + swz_x16(part);
            const float lg = s2 + __shfl_xor(s2, 32, 64);
            const bool ok = ((unsigned)(h + 4 * dh) < (unsigned)HH) &&
                            ((unsigned)(wown0 + 4 * dw) < (unsigned)WW);
            l0[d] = ok ? lg : -100.0f;
        }
        {
            float part = 0.f;
#pragma unroll
            for (int r = 0; r < 4; r++) {
                const float lv = fmaxf(c3_1[r], 0.01f * c3_1[r]);
                part = fmaf(w3c[r], lv, part);
            }
            float s2 = part + swz_x16(part);
            const float lg = s2 + __shfl_xor(s2, 32, 64);
            const bool ok = ((unsigned)(h + 4 * dh) < (unsigned)HH) &&
                            ((unsigned)(wown1 + 4 * dw) < (unsigned)WW);
            l1[d] = ok ? lg : -100.0f;
        }
    }

    // fused tail: logits replicated in all 64 lanes (DS reduce), so each
    // lane selects its own pixel's 9 logits and runs ONE softmax chain.
    // lanes 0..15 -> tile0 px wp0+lane; lanes 16..31 -> tile1 px wp0+lane.
    float ld[9];
#pragma unroll
    for (int d = 0; d < 9; d++) ld[d] = (lane & 16) ? l1[d] : l0[d];
    float mx = ld[0];
#pragma unroll
    for (int d = 1; d < 9; d++) mx = fmaxf(mx, ld[d]);
    float s = 0.f;
#pragma unroll
    for (int d = 0; d < 9; d++) {
        ld[d] = __expf(ld[d] - mx);
        s += ld[d];
    }
    const float inv = __builtin_amdgcn_rcpf(s);
    if (lane < 32) {  // 32 writer lanes -> 9 contiguous 128B stores (both tiles)
        float* op = out + (size_t)b * 9 * HW + (size_t)h * WW + (wp0 + lane);
#pragma unroll
        for (int d = 0; d < 9; d++) op[(size_t)d * HW] = ld[d] * inv;
    }
}

extern "C" void kernel_launch(void* const* d_in, const int* in_sizes, int n_in,
                              void* d_out, int out_size, void* d_ws, size_t ws_size,
                              hipStream_t stream) {
    const float* lr = (const float*)d_in[0];
    const float* hr = (const float*)d_in[1];
    // d_in[2], d_in[3] (lr_feature_r / hr_feature_r) are unused by the reference.
    const float* w0 = (const float*)d_in[4];
    const float* w1 = (const float*)d_in[5];
    const float* w2 = (const float*)d_in[6];
    const float* w3 = (const float*)d_in[7];
    float* out = (float*)d_out;

    const size_t alr_bytes = (size_t)BB * CH * CW * 32 * sizeof(float);  // 2 MB
    dim3 grid(WW / 32, HH / 4, BB);  // 2048 blocks of 256 thr (4 waves)

    if (ws_size >= alr_bytes) {
        float* alr = (float*)d_ws;
        alr_prepass<<<(BB * CH * CW + 255) / 256, 256, 0, stream>>>(lr, w0, alr);
        ercm_mfma<true><<<grid, 256, 0, stream>>>(hr, lr, alr, w0, w1, w2, w3, out);
    } else {
        ercm_mfma<false><<<grid, 256, 0, stream>>>(hr, lr, nullptr, w0, w1, w2, w3, out);
    }
}